// Round 4
// baseline (559.128 us; speedup 1.0000x reference)
//
#include <hip/hip_runtime.h>
#include <math.h>

#define B 4
#define C 64
#define L 4096
#define OUTC 64
#define SCALE 10.0f
#define THRESH 1e-3f

typedef float v2f __attribute__((ext_vector_type(2)));
typedef float v4f __attribute__((ext_vector_type(4)));

__device__ __forceinline__ v2f pk_fma(v2f a, v2f b, v2f c) {
#if __has_builtin(__builtin_elementwise_fma)
    return __builtin_elementwise_fma(a, b, c);
#else
    v2f r; r.x = fmaf(a.x, b.x, c.x); r.y = fmaf(a.y, b.y, c.y); return r;
#endif
}

// ---------------------------------------------------------------------------
// Projection: p = l2norm(W2 @ leaky(W1 @ x)) per column.
// 512 blocks (2 inputs x 4 batches x 64 column-tiles) x 256 threads.
// LDS layout Ht[h][l] (pad 65): bank = (65*h + l) % 32 -> 2 lanes/bank (free)
// for both the stage-1 writes and stage-2 reads.
// ---------------------------------------------------------------------------
__global__ void __launch_bounds__(256) proj_kernel(
    const float* __restrict__ q_in, const float* __restrict__ k_in,
    const float* __restrict__ W1, const float* __restrict__ W2,
    float* __restrict__ qp, float* __restrict__ kp)
{
    int bid   = blockIdx.x;        // 0..511
    int which = bid >> 8;          // 0 = query, 1 = key
    int b     = (bid >> 6) & 3;
    int l0    = (bid & 63) << 6;
    int t     = threadIdx.x;
    int g     = t >> 6;            // 0..3
    int l     = t & 63;

    const float* __restrict__ src =
        (which ? k_in : q_in) + (size_t)b * C * L + l0 + l;
    float* __restrict__ dst =
        (which ? kp : qp) + (size_t)b * OUTC * L + l0 + l;

    __shared__ float Ht[128][65];   // [h][l], pad 65 -> conflict-free
    __shared__ float red[4][64];

    // X column into registers (64 coalesced global loads)
    float xr[C];
    #pragma unroll
    for (int c = 0; c < C; ++c)
        xr[c] = src[(size_t)c * L];

    // Stage 1: H[o][l] for o in [g*32, g*32+32)
    #pragma unroll 1
    for (int oo = 0; oo < 32; oo += 4) {
        #pragma unroll
        for (int u = 0; u < 4; ++u) {
            int o = g * 32 + oo + u;
            float h0 = 0.f, h1 = 0.f, h2 = 0.f, h3 = 0.f;
            #pragma unroll
            for (int c = 0; c < C; c += 4) {
                h0 = fmaf(W1[o * C + c + 0], xr[c + 0], h0);
                h1 = fmaf(W1[o * C + c + 1], xr[c + 1], h1);
                h2 = fmaf(W1[o * C + c + 2], xr[c + 2], h2);
                h3 = fmaf(W1[o * C + c + 3], xr[c + 3], h3);
            }
            float h = (h0 + h1) + (h2 + h3);
            Ht[o][l] = (h >= 0.0f) ? h : 0.01f * h;   // LeakyReLU(0.01)
        }
    }
    __syncthreads();

    // Stage 2: Y[o][l] for o in [g*16, g*16+16)
    float y[16];
    #pragma unroll
    for (int u = 0; u < 16; ++u) y[u] = 0.f;

    #pragma unroll 1
    for (int hh = 0; hh < 2 * C; hh += 16) {
        float hr[16];
        #pragma unroll
        for (int r = 0; r < 16; ++r)
            hr[r] = Ht[hh + r][l];
        #pragma unroll
        for (int u = 0; u < 16; ++u) {
            int o = g * 16 + u;
            #pragma unroll
            for (int h = 0; h < 16; ++h)
                y[u] = fmaf(W2[o * (2 * C) + hh + h], hr[h], y[u]);
        }
    }

    // l2norm over all 64 output channels (cross-group via LDS)
    float ss = 0.f;
    #pragma unroll
    for (int u = 0; u < 16; ++u) ss = fmaf(y[u], y[u], ss);
    red[g][l] = ss;
    __syncthreads();
    float tot = red[0][l] + red[1][l] + red[2][l] + red[3][l];
    float inv = 1.0f / fmaxf(sqrtf(tot), 1e-12f);

    #pragma unroll
    for (int u = 0; u < 16; ++u)
        dst[(size_t)(g * 16 + u) * L] = y[u] * inv;
}

// ---------------------------------------------------------------------------
// Scores + softmax + threshold. One block per (b, 8-row tile): 2048 blocks
// x 512 threads. Thread: 8 rows x 8 cols (v4 slots t and t+512). 64 acc
// VGPRs; __launch_bounds__(512,4) -> <=128 VGPR -> 4 waves/SIMD -> 2
// blocks/CU so store tails overlap the co-resident block's compute.
// K (global) and q (LDS b128 broadcast) are prefetched one c ahead.
// ---------------------------------------------------------------------------
__global__ void __launch_bounds__(512, 4) scores_kernel(
    const float* __restrict__ qp, const float* __restrict__ kp,
    float* __restrict__ out)
{
    int bid = blockIdx.x;            // 0..2047; b major -> K[b] L2-resident
    int b   = bid >> 9;
    int l0  = (bid & 511) << 3;      // 8 rows
    int t   = threadIdx.x;           // 0..511

    const v4f* __restrict__ kp4 = (const v4f*)(kp + (size_t)b * C * L);

    __shared__ float qs[C][8];       // q tile, rows i=0..7 for all c
    {
        int c = t >> 3, i = t & 7;
        qs[c][i] = qp[((size_t)b * C + c) * L + l0 + i];
    }
    __syncthreads();

    v2f S[8][4];
    #pragma unroll
    for (int i = 0; i < 8; ++i)
        #pragma unroll
        for (int j = 0; j < 4; ++j) S[i][j] = (v2f){0.f, 0.f};

    // preload c = 0
    v4f ka = kp4[t];
    v4f kb = kp4[t + 512];
    v4f qv = *(const v4f*)&qs[0][0];
    v4f qw = *(const v4f*)&qs[0][4];

    #pragma unroll 4
    for (int c = 0; c < C; ++c) {
        // prefetch c+1 (last one wraps harmlessly to c=0)
        int cn = (c + 1) & (C - 1);
        v4f na = kp4[cn * (L / 4) + t];
        v4f nb = kp4[cn * (L / 4) + t + 512];
        v4f nqv = *(const v4f*)&qs[cn][0];
        v4f nqw = *(const v4f*)&qs[cn][4];

        v2f ka01 = {ka.x, ka.y}, ka23 = {ka.z, ka.w};
        v2f kb01 = {kb.x, kb.y}, kb23 = {kb.z, kb.w};
        float qarr[8] = {qv.x, qv.y, qv.z, qv.w, qw.x, qw.y, qw.z, qw.w};
        #pragma unroll
        for (int i = 0; i < 8; ++i) {
            v2f qq = {qarr[i], qarr[i]};
            S[i][0] = pk_fma(qq, ka01, S[i][0]);
            S[i][1] = pk_fma(qq, ka23, S[i][1]);
            S[i][2] = pk_fma(qq, kb01, S[i][2]);
            S[i][3] = pk_fma(qq, kb23, S[i][3]);
        }
        ka = na; kb = nb; qv = nqv; qw = nqw;
    }

    int wave = t >> 6, lane = t & 63;
    __shared__ float redm[8][8];
    __shared__ float reds[8][8];

    // scale, then row max (wave shuffle -> cross-wave LDS)
    #pragma unroll
    for (int i = 0; i < 8; ++i) {
        #pragma unroll
        for (int j = 0; j < 4; ++j) S[i][j] *= (v2f){SCALE, SCALE};
        float m = fmaxf(fmaxf(fmaxf(S[i][0].x, S[i][0].y),
                              fmaxf(S[i][1].x, S[i][1].y)),
                        fmaxf(fmaxf(S[i][2].x, S[i][2].y),
                              fmaxf(S[i][3].x, S[i][3].y)));
        #pragma unroll
        for (int off = 1; off < 64; off <<= 1)
            m = fmaxf(m, __shfl_xor(m, off));
        if (lane == 0) redm[i][wave] = m;
    }
    __syncthreads();

    float rowm[8];
    #pragma unroll
    for (int i = 0; i < 8; ++i) {
        float m = redm[i][0];
        #pragma unroll
        for (int w = 1; w < 8; ++w) m = fmaxf(m, redm[i][w]);
        rowm[i] = m;
    }

    // exp + row sum
    #pragma unroll
    for (int i = 0; i < 8; ++i) {
        float s = 0.f;
        #pragma unroll
        for (int j = 0; j < 4; ++j) {
            float ex = __expf(S[i][j].x - rowm[i]);
            float ey = __expf(S[i][j].y - rowm[i]);
            S[i][j] = (v2f){ex, ey};
            s += ex + ey;
        }
        #pragma unroll
        for (int off = 1; off < 64; off <<= 1)
            s += __shfl_xor(s, off);
        if (lane == 0) reds[i][wave] = s;
    }
    __syncthreads();

    v4f* __restrict__ out4 = (v4f*)out;
    #pragma unroll
    for (int i = 0; i < 8; ++i) {
        float tot = 0.f;
        #pragma unroll
        for (int w = 0; w < 8; ++w) tot += reds[i][w];
        float inv = 1.0f / tot;
        size_t rowbase = ((size_t)b * L + l0 + i) * (size_t)(L / 4);
        float w0 = S[i][0].x * inv, w1 = S[i][0].y * inv;
        float w2 = S[i][1].x * inv, w3 = S[i][1].y * inv;
        float w4 = S[i][2].x * inv, w5 = S[i][2].y * inv;
        float w6 = S[i][3].x * inv, w7 = S[i][3].y * inv;
        v4f r0 = {(w0 > THRESH) ? w0 : 0.f, (w1 > THRESH) ? w1 : 0.f,
                  (w2 > THRESH) ? w2 : 0.f, (w3 > THRESH) ? w3 : 0.f};
        v4f r1 = {(w4 > THRESH) ? w4 : 0.f, (w5 > THRESH) ? w5 : 0.f,
                  (w6 > THRESH) ? w6 : 0.f, (w7 > THRESH) ? w7 : 0.f};
        out4[rowbase + t]       = r0;
        out4[rowbase + t + 512] = r1;
    }
}

// ---------------------------------------------------------------------------
extern "C" void kernel_launch(void* const* d_in, const int* in_sizes, int n_in,
                              void* d_out, int out_size, void* d_ws, size_t ws_size,
                              hipStream_t stream) {
    const float* query = (const float*)d_in[0];
    const float* key   = (const float*)d_in[1];
    const float* W1    = (const float*)d_in[2];
    const float* W2    = (const float*)d_in[3];
    float* out = (float*)d_out;

    // workspace layout (floats): qp[4*64*4096] | kp[4*64*4096]
    float* qp = (float*)d_ws;
    float* kp = qp + (size_t)B * OUTC * L;

    hipLaunchKernelGGL(proj_kernel, dim3(512), dim3(256), 0, stream,
                       query, key, W1, W2, qp, kp);
    hipLaunchKernelGGL(scores_kernel, dim3(2048), dim3(512), 0, stream,
                       qp, kp, out);
}

// Round 5
// 436.471 us; speedup vs baseline: 1.2810x; 1.2810x over previous
//
#include <hip/hip_runtime.h>
#include <math.h>

#define B 4
#define C 64
#define L 4096
#define OUTC 64
#define SCALE 10.0f
#define THRESH 1e-3f

typedef float v4f __attribute__((ext_vector_type(4)));
typedef short bf16x8 __attribute__((ext_vector_type(8)));
typedef unsigned short us8 __attribute__((ext_vector_type(8)));

__device__ __forceinline__ unsigned short f2bf(float x) {
    unsigned int u = __float_as_uint(x);
    u += 0x7fffu + ((u >> 16) & 1u);          // round-to-nearest-even
    return (unsigned short)(u >> 16);
}
__device__ __forceinline__ float bf2f(unsigned short h) {
    return __uint_as_float(((unsigned int)h) << 16);
}
__device__ __forceinline__ v4f mfma16(bf16x8 a, bf16x8 b, v4f c) {
    return __builtin_amdgcn_mfma_f32_16x16x32_bf16(a, b, c, 0, 0, 0);
}

// ---------------------------------------------------------------------------
// Projection: p = l2norm(W2 @ leaky(W1 @ x)) per column, emitted as bf16
// hi/lo planes in ROW-MAJOR [b*L + l][c] layout (c contiguous) so the scores
// kernel can load MFMA A/B fragments directly (8 contiguous c per lane).
// 512 blocks (2 inputs x 4 batches x 64 column-tiles) x 256 threads.
// ---------------------------------------------------------------------------
__global__ void __launch_bounds__(256) proj_kernel(
    const float* __restrict__ q_in, const float* __restrict__ k_in,
    const float* __restrict__ W1, const float* __restrict__ W2,
    unsigned short* __restrict__ Qh, unsigned short* __restrict__ Ql,
    unsigned short* __restrict__ Kh, unsigned short* __restrict__ Kl)
{
    int bid   = blockIdx.x;        // 0..511
    int which = bid >> 8;          // 0 = query, 1 = key
    int b     = (bid >> 6) & 3;
    int l0    = (bid & 63) << 6;
    int t     = threadIdx.x;
    int g     = t >> 6;            // 0..3
    int l     = t & 63;

    const float* __restrict__ src =
        (which ? k_in : q_in) + (size_t)b * C * L + l0 + l;
    unsigned short* __restrict__ dh = which ? Kh : Qh;
    unsigned short* __restrict__ dl = which ? Kl : Ql;

    __shared__ float Ht[128][65];   // [h][l], pad 65 -> conflict-free
    __shared__ float red[4][64];

    float xr[C];
    #pragma unroll
    for (int c = 0; c < C; ++c)
        xr[c] = src[(size_t)c * L];

    // Stage 1: H[o][l] for o in [g*32, g*32+32)
    #pragma unroll 1
    for (int oo = 0; oo < 32; oo += 4) {
        #pragma unroll
        for (int u = 0; u < 4; ++u) {
            int o = g * 32 + oo + u;
            float h0 = 0.f, h1 = 0.f, h2 = 0.f, h3 = 0.f;
            #pragma unroll
            for (int c = 0; c < C; c += 4) {
                h0 = fmaf(W1[o * C + c + 0], xr[c + 0], h0);
                h1 = fmaf(W1[o * C + c + 1], xr[c + 1], h1);
                h2 = fmaf(W1[o * C + c + 2], xr[c + 2], h2);
                h3 = fmaf(W1[o * C + c + 3], xr[c + 3], h3);
            }
            float h = (h0 + h1) + (h2 + h3);
            Ht[o][l] = (h >= 0.0f) ? h : 0.01f * h;   // LeakyReLU(0.01)
        }
    }
    __syncthreads();

    // Stage 2: Y[o][l] for o in [g*16, g*16+16)
    float y[16];
    #pragma unroll
    for (int u = 0; u < 16; ++u) y[u] = 0.f;

    #pragma unroll 1
    for (int hh = 0; hh < 2 * C; hh += 16) {
        float hr[16];
        #pragma unroll
        for (int r = 0; r < 16; ++r)
            hr[r] = Ht[hh + r][l];
        #pragma unroll
        for (int u = 0; u < 16; ++u) {
            int o = g * 16 + u;
            #pragma unroll
            for (int h = 0; h < 16; ++h)
                y[u] = fmaf(W2[o * (2 * C) + hh + h], hr[h], y[u]);
        }
    }

    // l2norm over all 64 output channels (cross-group via LDS)
    float ss = 0.f;
    #pragma unroll
    for (int u = 0; u < 16; ++u) ss = fmaf(y[u], y[u], ss);
    red[g][l] = ss;
    __syncthreads();
    float tot = red[0][l] + red[1][l] + red[2][l] + red[3][l];
    float inv = 1.0f / fmaxf(sqrtf(tot), 1e-12f);

    // Emit bf16 hi/lo split: val = hi + lo with |val-(hi+lo)| ~ 2^-18*|val|
    unsigned short hs[16], ls[16];
    #pragma unroll
    for (int u = 0; u < 16; ++u) {
        float val = y[u] * inv;
        hs[u] = f2bf(val);
        ls[u] = f2bf(val - bf2f(hs[u]));
    }
    size_t rowoff = ((size_t)b * L + l0 + l) * 64 + (size_t)g * 16;
    *(us8*)(dh + rowoff)     = *(us8*)&hs[0];
    *(us8*)(dh + rowoff + 8) = *(us8*)&hs[8];
    *(us8*)(dl + rowoff)     = *(us8*)&ls[0];
    *(us8*)(dl + rowoff + 8) = *(us8*)&ls[8];
}

// ---------------------------------------------------------------------------
// Scores via MFMA bf16x3 + softmax(fixed shift) + threshold.
// 256 blocks = 4 batches x 64 row-tiles (64 q-rows each); 512 threads = 8
// waves; wave w owns contiguous columns [w*512, w*512+512) as 32 16-col
// tiles. S = Qh*Kh + Qh*Kl + Ql*Kh (lo*lo dropped, ~4e-5 logit error).
// Since |S| <= 10 (unit vectors * SCALE), softmax shift is the constant 10:
// pass 1 accumulates row sums of exp(S-10); pass 2 recomputes S (K hits L2)
// and writes thresholded w. A-frags (Q) persist in registers both passes.
// ---------------------------------------------------------------------------
__global__ void __launch_bounds__(512) scores_kernel(
    const unsigned short* __restrict__ Qh, const unsigned short* __restrict__ Ql,
    const unsigned short* __restrict__ Kh, const unsigned short* __restrict__ Kl,
    float* __restrict__ out)
{
    int bid  = blockIdx.x;          // 0..255
    int b    = bid >> 6;
    int r0   = (bid & 63) << 6;     // 64 rows
    int t    = threadIdx.x;
    int wave = t >> 6;
    int lane = t & 63;
    int quad = lane >> 4;
    int ln   = lane & 15;

    // A fragments: aQ[rt][c0][hi/lo], m = ln, k = quad*8 + j  (m120-verified)
    bf16x8 aQ[4][2][2];
    {
        size_t qbase = ((size_t)b * L + r0) * 64;
        #pragma unroll
        for (int rt = 0; rt < 4; ++rt) {
            size_t rowb = qbase + (size_t)(rt * 16 + ln) * 64 + quad * 8;
            #pragma unroll
            for (int c0 = 0; c0 < 2; ++c0) {
                aQ[rt][c0][0] = *(const bf16x8*)(Qh + rowb + c0 * 32);
                aQ[rt][c0][1] = *(const bf16x8*)(Ql + rowb + c0 * 32);
            }
        }
    }

    const size_t kbase = (size_t)b * L * 64;
    __shared__ float wsum[64][8];
    __shared__ float rinv[64];

    // ---------------- pass 1: row sums of exp(S - 10) ----------------
    v4f ps[4];
    #pragma unroll
    for (int rt = 0; rt < 4; ++rt) ps[rt] = (v4f){0.f, 0.f, 0.f, 0.f};

    #pragma unroll 1
    for (int ct = 0; ct < 32; ++ct) {
        int m0 = wave * 512 + ct * 16;
        size_t kr = kbase + (size_t)(m0 + ln) * 64 + quad * 8;
        bf16x8 bh0 = *(const bf16x8*)(Kh + kr);
        bf16x8 bl0 = *(const bf16x8*)(Kl + kr);
        bf16x8 bh1 = *(const bf16x8*)(Kh + kr + 32);
        bf16x8 bl1 = *(const bf16x8*)(Kl + kr + 32);
        #pragma unroll
        for (int rt = 0; rt < 4; ++rt) {
            v4f acc = (v4f){0.f, 0.f, 0.f, 0.f};
            acc = mfma16(aQ[rt][0][0], bh0, acc);
            acc = mfma16(aQ[rt][0][1], bh0, acc);
            acc = mfma16(aQ[rt][0][0], bl0, acc);
            acc = mfma16(aQ[rt][1][0], bh1, acc);
            acc = mfma16(aQ[rt][1][1], bh1, acc);
            acc = mfma16(aQ[rt][1][0], bl1, acc);
            #pragma unroll
            for (int r = 0; r < 4; ++r)
                ps[rt][r] += __expf(fmaf(SCALE, acc[r], -SCALE));
        }
    }

    // reduce over the 16 ln-lanes (cols) per row, then across waves via LDS
    #pragma unroll
    for (int rt = 0; rt < 4; ++rt) {
        #pragma unroll
        for (int r = 0; r < 4; ++r) {
            float s = ps[rt][r];
            s += __shfl_xor(s, 1);
            s += __shfl_xor(s, 2);
            s += __shfl_xor(s, 4);
            s += __shfl_xor(s, 8);
            if (ln == 0) wsum[rt * 16 + quad * 4 + r][wave] = s;
        }
    }
    __syncthreads();
    if (t < 64) {
        float s = 0.f;
        #pragma unroll
        for (int w = 0; w < 8; ++w) s += wsum[t][w];
        rinv[t] = 1.0f / s;
    }
    __syncthreads();

    float rv[4][4];
    #pragma unroll
    for (int rt = 0; rt < 4; ++rt)
        #pragma unroll
        for (int r = 0; r < 4; ++r)
            rv[rt][r] = rinv[rt * 16 + quad * 4 + r];

    // ---------------- pass 2: recompute, normalize, threshold, store ------
    float* __restrict__ outb = out + ((size_t)b * L + r0) * L;
    #pragma unroll 1
    for (int ct = 0; ct < 32; ++ct) {
        int m0 = wave * 512 + ct * 16;
        size_t kr = kbase + (size_t)(m0 + ln) * 64 + quad * 8;
        bf16x8 bh0 = *(const bf16x8*)(Kh + kr);
        bf16x8 bl0 = *(const bf16x8*)(Kl + kr);
        bf16x8 bh1 = *(const bf16x8*)(Kh + kr + 32);
        bf16x8 bl1 = *(const bf16x8*)(Kl + kr + 32);
        #pragma unroll
        for (int rt = 0; rt < 4; ++rt) {
            v4f acc = (v4f){0.f, 0.f, 0.f, 0.f};
            acc = mfma16(aQ[rt][0][0], bh0, acc);
            acc = mfma16(aQ[rt][0][1], bh0, acc);
            acc = mfma16(aQ[rt][0][0], bl0, acc);
            acc = mfma16(aQ[rt][1][0], bh1, acc);
            acc = mfma16(aQ[rt][1][1], bh1, acc);
            acc = mfma16(aQ[rt][1][0], bl1, acc);
            #pragma unroll
            for (int r = 0; r < 4; ++r) {
                float w = __expf(fmaf(SCALE, acc[r], -SCALE)) * rv[rt][r];
                w = (w > THRESH) ? w : 0.f;
                // C/D layout: col = ln, row = quad*4 + r (m89/m91-verified)
                outb[(size_t)(rt * 16 + quad * 4 + r) * L + m0 + ln] = w;
            }
        }
    }
}

// ---------------------------------------------------------------------------
extern "C" void kernel_launch(void* const* d_in, const int* in_sizes, int n_in,
                              void* d_out, int out_size, void* d_ws, size_t ws_size,
                              hipStream_t stream) {
    const float* query = (const float*)d_in[0];
    const float* key   = (const float*)d_in[1];
    const float* W1    = (const float*)d_in[2];
    const float* W2    = (const float*)d_in[3];
    float* out = (float*)d_out;

    // ws layout (ushorts): Qh | Ql | Kh | Kl, each B*L*OUTC = 1048576 elems
    unsigned short* Qh = (unsigned short*)d_ws;
    unsigned short* Ql = Qh + (size_t)B * L * OUTC;
    unsigned short* Kh = Ql + (size_t)B * L * OUTC;
    unsigned short* Kl = Kh + (size_t)B * L * OUTC;

    hipLaunchKernelGGL(proj_kernel, dim3(512), dim3(256), 0, stream,
                       query, key, W1, W2, Qh, Ql, Kh, Kl);
    hipLaunchKernelGGL(scores_kernel, dim3(256), dim3(512), 0, stream,
                       Qh, Ql, Kh, Kl, out);
}

// Round 6
// 435.820 us; speedup vs baseline: 1.2829x; 1.0015x over previous
//
#include <hip/hip_runtime.h>
#include <math.h>

#define B 4
#define C 64
#define L 4096
#define OUTC 64
#define SCALE 10.0f
#define THRESH 1e-3f

typedef float v4f __attribute__((ext_vector_type(4)));
typedef short bf16x8 __attribute__((ext_vector_type(8)));
typedef unsigned short us8 __attribute__((ext_vector_type(8)));

__device__ __forceinline__ unsigned short f2bf(float x) {
    unsigned int u = __float_as_uint(x);
    u += 0x7fffu + ((u >> 16) & 1u);          // round-to-nearest-even
    return (unsigned short)(u >> 16);
}
__device__ __forceinline__ float bf2f(unsigned short h) {
    return __uint_as_float(((unsigned int)h) << 16);
}
__device__ __forceinline__ v4f mfma16(bf16x8 a, bf16x8 b, v4f c) {
    return __builtin_amdgcn_mfma_f32_16x16x32_bf16(a, b, c, 0, 0, 0);
}

// ---------------------------------------------------------------------------
// Projection: p = l2norm(W2 @ leaky(W1 @ x)) per column, emitted as bf16
// hi/lo planes in ROW-MAJOR [b*L + l][c] layout (c contiguous) so the scores
// kernel can load MFMA A/B fragments directly (8 contiguous c per lane).
// 512 blocks (2 inputs x 4 batches x 64 column-tiles) x 256 threads.
// ---------------------------------------------------------------------------
__global__ void __launch_bounds__(256) proj_kernel(
    const float* __restrict__ q_in, const float* __restrict__ k_in,
    const float* __restrict__ W1, const float* __restrict__ W2,
    unsigned short* __restrict__ Qh, unsigned short* __restrict__ Ql,
    unsigned short* __restrict__ Kh, unsigned short* __restrict__ Kl)
{
    int bid   = blockIdx.x;        // 0..511
    int which = bid >> 8;          // 0 = query, 1 = key
    int b     = (bid >> 6) & 3;
    int l0    = (bid & 63) << 6;
    int t     = threadIdx.x;
    int g     = t >> 6;            // 0..3
    int l     = t & 63;

    const float* __restrict__ src =
        (which ? k_in : q_in) + (size_t)b * C * L + l0 + l;
    unsigned short* __restrict__ dh = which ? Kh : Qh;
    unsigned short* __restrict__ dl = which ? Kl : Ql;

    __shared__ float Ht[128][65];   // [h][l], pad 65 -> conflict-free
    __shared__ float red[4][64];

    float xr[C];
    #pragma unroll
    for (int c = 0; c < C; ++c)
        xr[c] = src[(size_t)c * L];

    // Stage 1: H[o][l] for o in [g*32, g*32+32)
    #pragma unroll 1
    for (int oo = 0; oo < 32; oo += 4) {
        #pragma unroll
        for (int u = 0; u < 4; ++u) {
            int o = g * 32 + oo + u;
            float h0 = 0.f, h1 = 0.f, h2 = 0.f, h3 = 0.f;
            #pragma unroll
            for (int c = 0; c < C; c += 4) {
                h0 = fmaf(W1[o * C + c + 0], xr[c + 0], h0);
                h1 = fmaf(W1[o * C + c + 1], xr[c + 1], h1);
                h2 = fmaf(W1[o * C + c + 2], xr[c + 2], h2);
                h3 = fmaf(W1[o * C + c + 3], xr[c + 3], h3);
            }
            float h = (h0 + h1) + (h2 + h3);
            Ht[o][l] = (h >= 0.0f) ? h : 0.01f * h;   // LeakyReLU(0.01)
        }
    }
    __syncthreads();

    // Stage 2: Y[o][l] for o in [g*16, g*16+16)
    float y[16];
    #pragma unroll
    for (int u = 0; u < 16; ++u) y[u] = 0.f;

    #pragma unroll 1
    for (int hh = 0; hh < 2 * C; hh += 16) {
        float hr[16];
        #pragma unroll
        for (int r = 0; r < 16; ++r)
            hr[r] = Ht[hh + r][l];
        #pragma unroll
        for (int u = 0; u < 16; ++u) {
            int o = g * 16 + u;
            #pragma unroll
            for (int h = 0; h < 16; ++h)
                y[u] = fmaf(W2[o * (2 * C) + hh + h], hr[h], y[u]);
        }
    }

    // l2norm over all 64 output channels (cross-group via LDS)
    float ss = 0.f;
    #pragma unroll
    for (int u = 0; u < 16; ++u) ss = fmaf(y[u], y[u], ss);
    red[g][l] = ss;
    __syncthreads();
    float tot = red[0][l] + red[1][l] + red[2][l] + red[3][l];
    float inv = 1.0f / fmaxf(sqrtf(tot), 1e-12f);

    // Emit bf16 hi/lo split: val = hi + lo with |val-(hi+lo)| ~ 2^-18*|val|
    unsigned short hs[16], ls[16];
    #pragma unroll
    for (int u = 0; u < 16; ++u) {
        float val = y[u] * inv;
        hs[u] = f2bf(val);
        ls[u] = f2bf(val - bf2f(hs[u]));
    }
    size_t rowoff = ((size_t)b * L + l0 + l) * 64 + (size_t)g * 16;
    *(us8*)(dh + rowoff)     = *(us8*)&hs[0];
    *(us8*)(dh + rowoff + 8) = *(us8*)&hs[8];
    *(us8*)(dl + rowoff)     = *(us8*)&ls[0];
    *(us8*)(dl + rowoff + 8) = *(us8*)&ls[8];
}

// ---------------------------------------------------------------------------
// Scores via MFMA bf16x3 + softmax(fixed shift 10) + threshold.
// 512 blocks = 4 batches x 128 row-tiles (32 q-rows each); 512 threads = 8
// waves; wave w owns cols [w*512, w*512+512) as 32 16-col tiles.
// __launch_bounds__(512,4): <=128 VGPR -> 2 blocks/CU, 4 waves/SIMD.
// K fragments prefetched one ct ahead; output uses nontemporal stores so
// K[b] (1 MB hi+lo) stays L2-resident across ct and across the two passes.
// S = Qh*Kh + Qh*Kl + Ql*Kh (lo*lo dropped, ~4e-5 logit error). |S|<=10 so
// the softmax shift is the constant 10 (exp(S-10) in [2e-9,1], no max pass).
// ---------------------------------------------------------------------------
__global__ void __launch_bounds__(512, 4) scores_kernel(
    const unsigned short* __restrict__ Qh, const unsigned short* __restrict__ Ql,
    const unsigned short* __restrict__ Kh, const unsigned short* __restrict__ Kl,
    float* __restrict__ out)
{
    int bid  = blockIdx.x;          // 0..511
    int b    = bid >> 7;
    int r0   = (bid & 127) << 5;    // 32 rows
    int t    = threadIdx.x;
    int wave = t >> 6;
    int lane = t & 63;
    int quad = lane >> 4;
    int ln   = lane & 15;

    // A fragments: aQ[rt][c0][hi/lo], m = ln, k = quad*8 + j  (m120-verified)
    bf16x8 aQ[2][2][2];
    {
        size_t qbase = ((size_t)b * L + r0) * 64;
        #pragma unroll
        for (int rt = 0; rt < 2; ++rt) {
            size_t rowb = qbase + (size_t)(rt * 16 + ln) * 64 + quad * 8;
            #pragma unroll
            for (int c0 = 0; c0 < 2; ++c0) {
                aQ[rt][c0][0] = *(const bf16x8*)(Qh + rowb + c0 * 32);
                aQ[rt][c0][1] = *(const bf16x8*)(Ql + rowb + c0 * 32);
            }
        }
    }

    const size_t kbase = (size_t)b * L * 64;
    __shared__ float wsum[32][8];
    __shared__ float rinv[32];

    // ---------------- pass 1: row sums of exp(S - 10) ----------------
    v4f ps[2];
    ps[0] = (v4f){0.f, 0.f, 0.f, 0.f};
    ps[1] = (v4f){0.f, 0.f, 0.f, 0.f};

    {
        size_t kr0 = kbase + (size_t)(wave * 512 + ln) * 64 + quad * 8;
        bf16x8 bh0 = *(const bf16x8*)(Kh + kr0);
        bf16x8 bl0 = *(const bf16x8*)(Kl + kr0);
        bf16x8 bh1 = *(const bf16x8*)(Kh + kr0 + 32);
        bf16x8 bl1 = *(const bf16x8*)(Kl + kr0 + 32);

        #pragma unroll 1
        for (int ct = 0; ct < 32; ++ct) {
            int ctn = (ct + 1) & 31;   // prefetch (wraps harmlessly)
            size_t krn = kbase + (size_t)(wave * 512 + ctn * 16 + ln) * 64 + quad * 8;
            bf16x8 nh0 = *(const bf16x8*)(Kh + krn);
            bf16x8 nl0 = *(const bf16x8*)(Kl + krn);
            bf16x8 nh1 = *(const bf16x8*)(Kh + krn + 32);
            bf16x8 nl1 = *(const bf16x8*)(Kl + krn + 32);

            #pragma unroll
            for (int rt = 0; rt < 2; ++rt) {
                v4f acc = (v4f){0.f, 0.f, 0.f, 0.f};
                acc = mfma16(aQ[rt][0][0], bh0, acc);
                acc = mfma16(aQ[rt][0][1], bh0, acc);
                acc = mfma16(aQ[rt][0][0], bl0, acc);
                acc = mfma16(aQ[rt][1][0], bh1, acc);
                acc = mfma16(aQ[rt][1][1], bh1, acc);
                acc = mfma16(aQ[rt][1][0], bl1, acc);
                #pragma unroll
                for (int r = 0; r < 4; ++r)
                    ps[rt][r] += __expf(fmaf(SCALE, acc[r], -SCALE));
            }
            bh0 = nh0; bl0 = nl0; bh1 = nh1; bl1 = nl1;
        }
    }

    // reduce over the 16 ln-lanes (cols) per row, then across waves via LDS
    #pragma unroll
    for (int rt = 0; rt < 2; ++rt) {
        #pragma unroll
        for (int r = 0; r < 4; ++r) {
            float s = ps[rt][r];
            s += __shfl_xor(s, 1);
            s += __shfl_xor(s, 2);
            s += __shfl_xor(s, 4);
            s += __shfl_xor(s, 8);
            if (ln == 0) wsum[rt * 16 + quad * 4 + r][wave] = s;
        }
    }
    __syncthreads();
    if (t < 32) {
        float s = 0.f;
        #pragma unroll
        for (int w = 0; w < 8; ++w) s += wsum[t][w];
        rinv[t] = 1.0f / s;
    }
    __syncthreads();

    float rv[2][4];
    #pragma unroll
    for (int rt = 0; rt < 2; ++rt)
        #pragma unroll
        for (int r = 0; r < 4; ++r)
            rv[rt][r] = rinv[rt * 16 + quad * 4 + r];

    // ---------------- pass 2: recompute, normalize, threshold, store ------
    float* __restrict__ outb = out + ((size_t)b * L + r0) * L;
    {
        size_t kr0 = kbase + (size_t)(wave * 512 + ln) * 64 + quad * 8;
        bf16x8 bh0 = *(const bf16x8*)(Kh + kr0);
        bf16x8 bl0 = *(const bf16x8*)(Kl + kr0);
        bf16x8 bh1 = *(const bf16x8*)(Kh + kr0 + 32);
        bf16x8 bl1 = *(const bf16x8*)(Kl + kr0 + 32);

        #pragma unroll 1
        for (int ct = 0; ct < 32; ++ct) {
            int m0  = wave * 512 + ct * 16;
            int ctn = (ct + 1) & 31;
            size_t krn = kbase + (size_t)(wave * 512 + ctn * 16 + ln) * 64 + quad * 8;
            bf16x8 nh0 = *(const bf16x8*)(Kh + krn);
            bf16x8 nl0 = *(const bf16x8*)(Kl + krn);
            bf16x8 nh1 = *(const bf16x8*)(Kh + krn + 32);
            bf16x8 nl1 = *(const bf16x8*)(Kl + krn + 32);

            #pragma unroll
            for (int rt = 0; rt < 2; ++rt) {
                v4f acc = (v4f){0.f, 0.f, 0.f, 0.f};
                acc = mfma16(aQ[rt][0][0], bh0, acc);
                acc = mfma16(aQ[rt][0][1], bh0, acc);
                acc = mfma16(aQ[rt][0][0], bl0, acc);
                acc = mfma16(aQ[rt][1][0], bh1, acc);
                acc = mfma16(aQ[rt][1][1], bh1, acc);
                acc = mfma16(aQ[rt][1][0], bl1, acc);
                #pragma unroll
                for (int r = 0; r < 4; ++r) {
                    float w = __expf(fmaf(SCALE, acc[r], -SCALE)) * rv[rt][r];
                    w = (w > THRESH) ? w : 0.f;
                    // C/D layout: col = ln, row = quad*4 + r (m89/m91)
                    __builtin_nontemporal_store(
                        w, outb + (size_t)(rt * 16 + quad * 4 + r) * L + m0 + ln);
                }
            }
            bh0 = nh0; bl0 = nl0; bh1 = nh1; bl1 = nl1;
        }
    }
}

// ---------------------------------------------------------------------------
extern "C" void kernel_launch(void* const* d_in, const int* in_sizes, int n_in,
                              void* d_out, int out_size, void* d_ws, size_t ws_size,
                              hipStream_t stream) {
    const float* query = (const float*)d_in[0];
    const float* key   = (const float*)d_in[1];
    const float* W1    = (const float*)d_in[2];
    const float* W2    = (const float*)d_in[3];
    float* out = (float*)d_out;

    // ws layout (ushorts): Qh | Ql | Kh | Kl, each B*L*OUTC = 1048576 elems
    unsigned short* Qh = (unsigned short*)d_ws;
    unsigned short* Ql = Qh + (size_t)B * L * OUTC;
    unsigned short* Kh = Ql + (size_t)B * L * OUTC;
    unsigned short* Kl = Kh + (size_t)B * L * OUTC;

    hipLaunchKernelGGL(proj_kernel, dim3(512), dim3(256), 0, stream,
                       query, key, W1, W2, Qh, Ql, Kh, Kl);
    hipLaunchKernelGGL(scores_kernel, dim3(512), dim3(512), 0, stream,
                       Qh, Ql, Kh, Kl, out);
}